// Round 5
// baseline (871.362 us; speedup 1.0000x reference)
//
#include <hip/hip_runtime.h>
#include <cfloat>
#include <cmath>

#define F_IN 128
#define HID 512

typedef short bf16x8 __attribute__((ext_vector_type(8)));
typedef float f32x4 __attribute__((ext_vector_type(4)));

// ---- bf16 split helpers (RNE) ----
__device__ static inline void split_bf16(float v, short& hi, short& lo) {
    unsigned u = __float_as_uint(v);
    unsigned r = u + 0x7FFF + ((u >> 16) & 1);
    hi = (short)(r >> 16);
    float hf = __uint_as_float(((unsigned)(unsigned short)hi) << 16);
    float res = v - hf;
    unsigned u2 = __float_as_uint(res);
    unsigned r2 = u2 + 0x7FFF + ((u2 >> 16) & 1);
    lo = (short)(r2 >> 16);
}

// monotone float->uint map: a<b (float) <=> enc(a)<enc(b) (unsigned)
__device__ static inline unsigned enc_f32(float f) {
    unsigned u = __float_as_uint(f);
    return (u >> 31) ? ~u : (u | 0x80000000u);
}

__device__ static inline void gload_lds16(const void* g, void* l) {
    __builtin_amdgcn_global_load_lds(
        (const __attribute__((address_space(1))) unsigned int*)g,
        (__attribute__((address_space(3))) unsigned int*)l,
        16, 0, 0);
}

// ---------------- small utility kernels ----------------

__global__ void zero_kernel(int* __restrict__ a, int n) {
    int i = blockIdx.x * blockDim.x + threadIdx.x;
    if (i < n) a[i] = 0;
}

__global__ void count_in_kernel(const int* __restrict__ dst, int* __restrict__ cnt, int E) {
    int e = blockIdx.x * blockDim.x + threadIdx.x;
    if (e < E) atomicAdd(&cnt[dst[e]], 1);
}

// single-block scan (exclusive prefix sum); also writes offs[n] = total
__global__ void scan_kernel(const int* __restrict__ cnt, int* __restrict__ offs, int n) {
    __shared__ int buf[1024];
    __shared__ int carry_s;
    if (threadIdx.x == 0) carry_s = 0;
    __syncthreads();
    for (int base = 0; base < n; base += 1024) {
        int i = base + threadIdx.x;
        int v = (i < n) ? cnt[i] : 0;
        buf[threadIdx.x] = v;
        __syncthreads();
        for (int s = 1; s < 1024; s <<= 1) {
            int t = (threadIdx.x >= s) ? buf[threadIdx.x - s] : 0;
            __syncthreads();
            buf[threadIdx.x] += t;
            __syncthreads();
        }
        int total = buf[1023];
        if (i < n) offs[i] = carry_s + buf[threadIdx.x] - v;
        __syncthreads();
        if (threadIdx.x == 0) carry_s += total;
        __syncthreads();
    }
    if (threadIdx.x == 0) offs[n] = carry_s;
}

// dis + graph-boundary starts, merged (both N-grids)
__global__ void dis_starts_kernel(const int* __restrict__ offs, float* __restrict__ dis,
                                  const int* __restrict__ batch, int* __restrict__ starts,
                                  int n, int G) {
    int i = blockIdx.x * blockDim.x + threadIdx.x;
    if (i >= n) return;
    dis[i] = rsqrtf((float)(offs[i + 1] - offs[i] + 1));  // +1 self-loop
    int b = batch[i];
    if (i == 0) {
        for (int g = 0; g <= b; g++) starts[g] = 0;
    } else {
        int bp = batch[i - 1];
        for (int g = bp + 1; g <= b; g++) starts[g] = i;
    }
    if (i == n - 1) {
        for (int g = b + 1; g <= G; g++) starts[g] = n;
    }
}

// countdown-cursor fill: reuses cnt (holds deg) as cursor via atomicSub
__global__ void fill_csr_kernel(const int* __restrict__ src, const int* __restrict__ dst,
                                const int* __restrict__ offs, int* __restrict__ cnt,
                                unsigned short* __restrict__ csr, int E) {
    int e = blockIdx.x * blockDim.x + threadIdx.x;
    if (e < E) {
        int d = dst[e];
        int p = atomicSub(&cnt[d], 1);  // returns old value in [1, deg]
        csr[offs[d] + p - 1] = (unsigned short)src[e];
    }
}

// all-layer W fp32 -> bf16 hi/lo planes (single launch, concatenated)
__global__ void wconv_kernel(const float* __restrict__ W1, const float* __restrict__ W2,
                             const float* __restrict__ W3, const float* __restrict__ W4,
                             short* __restrict__ Whi, short* __restrict__ Wlo) {
    int i = blockIdx.x * blockDim.x + threadIdx.x;
    const int n1 = HID * F_IN, nk = HID * HID;
    float v;
    if (i < n1) v = W1[i];
    else if (i < n1 + nk) v = W2[i - n1];
    else if (i < n1 + 2 * nk) v = W3[i - n1 - nk];
    else if (i < n1 + 3 * nk) v = W4[i - n1 - 2 * nk];
    else return;
    short h, l;
    split_bf16(v, h, l);
    Whi[i] = h;
    Wlo[i] = l;
}

// pool accumulators live IN d_out: per graph g, uints [0,2048) = max keys,
// ints [2048,4096) = positive counts. Init keys to enc(-inf)=0x007FFFFF, counts 0.
__global__ void pool_init_kernel(unsigned* __restrict__ out, int n) {
    int i = blockIdx.x * blockDim.x + threadIdx.x;
    if (i < n) out[i] = ((i & 4095) < 2048) ? 0x007FFFFFu : 0u;
}

__global__ void pool_fin_kernel(float* __restrict__ out, const int* __restrict__ starts, int G) {
    int idx = blockIdx.x * blockDim.x + threadIdx.x;  // over G*2048
    if (idx >= G * 2048) return;
    int g = idx >> 11, lc = idx & 2047;
    unsigned k = ((unsigned*)out)[(size_t)g * 4096 + lc];
    unsigned u = (k & 0x80000000u) ? (k & 0x7FFFFFFFu) : ~k;
    out[(size_t)g * 4096 + lc] = __uint_as_float(u);
    int cnt = ((int*)out)[(size_t)g * 4096 + 2048 + lc];
    int nc = starts[g + 1] - starts[g];
    out[(size_t)g * 4096 + 2048 + lc] = (float)cnt / (float)(nc > 0 ? nc : 1);
}

// -------- XCD-affine chunked aggregation + fused bf16-pair conversion --------
// out_i = dis_i * (dis_i*H_i + sum_j dis_j*H_j), written as bf16 hi/lo planes.
// blk -> node group blk/CHUNKS (4 nodes, one per wave), chunk = blk%CHUNKS
// (tracks round-robin XCD mapping: each XCD L2 sees only its 64-col H slice).
// 256 threads = 4 waves per block for high wave occupancy; 8-deep gather pipeline.
template <int F, int CHUNKS>
__global__ __launch_bounds__(256) void agg_chunk_kernel(
    const float* __restrict__ H, const float* __restrict__ dis,
    const int* __restrict__ offs, const unsigned short* __restrict__ csr,
    short* __restrict__ Ahi, short* __restrict__ Alo, int n) {
    int blk = blockIdx.x;
    int i = (blk / CHUNKS) * 4 + (threadIdx.x >> 6);
    if (i >= n) return;
    int chunk = blk % CHUNKS;
    int t = threadIdx.x & 63;
    int col = chunk * 64 + t;
    const float* Hc = H + col;

    float di = dis[i];
    float a = di * Hc[(size_t)i * F];
    int e = offs[i], e1 = offs[i + 1];
    // 8-way software-pipelined gather (R3-proven shape)
    for (; e + 8 <= e1; e += 8) {
        int j0 = csr[e],     j1 = csr[e + 1], j2 = csr[e + 2], j3 = csr[e + 3];
        int j4 = csr[e + 4], j5 = csr[e + 5], j6 = csr[e + 6], j7 = csr[e + 7];
        float d0 = dis[j0], d1 = dis[j1], d2 = dis[j2], d3 = dis[j3];
        float d4 = dis[j4], d5 = dis[j5], d6 = dis[j6], d7 = dis[j7];
        float r0 = Hc[(size_t)j0 * F], r1 = Hc[(size_t)j1 * F];
        float r2 = Hc[(size_t)j2 * F], r3 = Hc[(size_t)j3 * F];
        float r4 = Hc[(size_t)j4 * F], r5 = Hc[(size_t)j5 * F];
        float r6 = Hc[(size_t)j6 * F], r7 = Hc[(size_t)j7 * F];
        a += d0 * r0 + d1 * r1 + d2 * r2 + d3 * r3;
        a += d4 * r4 + d5 * r5 + d6 * r6 + d7 * r7;
    }
    for (; e < e1; e++) {
        int j = csr[e];
        a += dis[j] * Hc[(size_t)j * F];
    }
    a *= di;
    short h, l;
    split_bf16(a, h, l);
    Ahi[(size_t)i * F + col] = h;
    Alo[(size_t)i * F + col] = l;
}

// -------- split-bf16 MFMA GEMM + fused pooling epilogue (register-slim) --------
// C[M,N] = A[M,K] @ W[N,K]^T + bias; 3 products hi*hi + hi*lo + lo*hi.
// Epilogue processes one output column (j) at a time: per-graph running
// (max, poscnt) in 3 scalars, flushed via atomicMax(enc)/atomicAdd into d_out.
__global__ __launch_bounds__(256) void gemm_mfma_kernel(
    const short* __restrict__ Ahi, const short* __restrict__ Alo,
    const short* __restrict__ Whi, const short* __restrict__ Wlo,
    const float* __restrict__ bias, float* __restrict__ C,
    const int* __restrict__ batch, float* __restrict__ pool, int layer, int write_c,
    int M, int K, int Nout) {
    __shared__ __attribute__((aligned(16))) short lds[4][4096];

    int tid = threadIdx.x;
    int w = tid >> 6, l = tid & 63;
    int m0 = blockIdx.x * 128, n0 = blockIdx.y * 128;
    int lrow = l & 15, lq = l >> 4;

    const short* gp = (w == 0) ? Ahi : (w == 1) ? Alo : (w == 2) ? Whi : Wlo;
    int base_mn = (w < 2) ? m0 : n0;

    f32x4 acc[4][4];
    #pragma unroll
    for (int i = 0; i < 4; i++)
        #pragma unroll
        for (int j = 0; j < 4; j++) acc[i][j] = (f32x4){0.f, 0.f, 0.f, 0.f};

    int wm = w >> 1, wn = w & 1;

    for (int k0 = 0; k0 < K; k0 += 32) {
        const short* gbase = gp + (size_t)(base_mn + lrow) * K + (k0 + lq * 8);
        #pragma unroll
        for (int s = 0; s < 8; s++) {
            gload_lds16(gbase + (size_t)s * 16 * K, &lds[w][s * 64 * 8]);
        }
        __syncthreads();

        bf16x8 ah[4], al[4], wh[4], wl[4];
        #pragma unroll
        for (int i = 0; i < 4; i++) {
            int sA = wm * 4 + i;
            ah[i] = *(const bf16x8*)&lds[0][(sA * 64 + l) * 8];
            al[i] = *(const bf16x8*)&lds[1][(sA * 64 + l) * 8];
            int sW = wn * 4 + i;
            wh[i] = *(const bf16x8*)&lds[2][(sW * 64 + l) * 8];
            wl[i] = *(const bf16x8*)&lds[3][(sW * 64 + l) * 8];
        }
        #pragma unroll
        for (int i = 0; i < 4; i++)
            #pragma unroll
            for (int j = 0; j < 4; j++) {
                acc[i][j] = __builtin_amdgcn_mfma_f32_16x16x32_bf16(ah[i], wh[j], acc[i][j], 0, 0, 0);
                acc[i][j] = __builtin_amdgcn_mfma_f32_16x16x32_bf16(ah[i], wl[j], acc[i][j], 0, 0, 0);
                acc[i][j] = __builtin_amdgcn_mfma_f32_16x16x32_bf16(al[i], wh[j], acc[i][j], 0, 0, 0);
            }
        __syncthreads();
    }

    // ---- epilogue: one column at a time, minimal live registers ----
    #pragma unroll
    for (int j = 0; j < 4; j++) {
        int col = n0 + (wn * 4 + j) * 16 + lrow;
        float bv = bias[col];
        float cmax = -INFINITY;
        int ccnt = 0;
        int curg = -1;
        #pragma unroll
        for (int i = 0; i < 4; i++) {
            #pragma unroll
            for (int r = 0; r < 4; r++) {
                int mm = m0 + (wm * 4 + i) * 16 + lq * 4 + r;   // strictly increasing
                if (mm < M) {
                    float v = acc[i][j][r] + bv;
                    if (write_c) C[(size_t)mm * Nout + col] = v;
                    int g = batch[mm];
                    if (g != curg) {
                        if (curg >= 0) {
                            size_t base = (size_t)curg * 4096 + layer * HID + col;
                            atomicMax((unsigned*)pool + base, enc_f32(cmax));
                            atomicAdd((int*)pool + base + 2048, ccnt);
                        }
                        curg = g; cmax = -INFINITY; ccnt = 0;
                    }
                    cmax = fmaxf(cmax, v);
                    ccnt += (v > 0.0f) ? 1 : 0;
                }
            }
        }
        if (curg >= 0) {
            size_t base = (size_t)curg * 4096 + layer * HID + col;
            atomicMax((unsigned*)pool + base, enc_f32(cmax));
            atomicAdd((int*)pool + base + 2048, ccnt);
        }
    }
}

// ---------------- launcher ----------------
extern "C" void kernel_launch(void* const* d_in, const int* in_sizes, int n_in,
                              void* d_out, int out_size, void* d_ws, size_t ws_size,
                              hipStream_t stream) {
    const float* x     = (const float*)d_in[0];
    const int*   eidx  = (const int*)d_in[1];
    const int*   batch = (const int*)d_in[2];
    const float* W1 = (const float*)d_in[5];
    const float* b1 = (const float*)d_in[6];
    const float* W2 = (const float*)d_in[7];
    const float* b2 = (const float*)d_in[8];
    const float* W3 = (const float*)d_in[9];
    const float* b3 = (const float*)d_in[10];
    const float* W4 = (const float*)d_in[11];
    const float* b4 = (const float*)d_in[12];
    float* out = (float*)d_out;

    const int N = in_sizes[0] / F_IN;   // 20000
    const int E = in_sizes[1] / 2;      // 320000
    const int G = out_size / (8 * HID); // 256

    const int* src = eidx;
    const int* dst = eidx + E;

    // workspace layout (16B-aligned segments first)
    const size_t nW = (size_t)HID * F_IN + 3 * (size_t)HID * HID;
    char* w = (char*)d_ws;
    short* Ahi = (short*)w; w += (size_t)N * HID * sizeof(short);
    short* Alo = (short*)w; w += (size_t)N * HID * sizeof(short);
    float* H   = (float*)w; w += (size_t)N * HID * sizeof(float);
    short* Whi = (short*)w; w += nW * sizeof(short);
    short* Wlo = (short*)w; w += nW * sizeof(short);
    int* offs  = (int*)w;   w += (size_t)(N + 4) * sizeof(int);
    unsigned short* csr = (unsigned short*)w; w += (size_t)E * sizeof(unsigned short);
    int* cnt   = (int*)w;   w += (size_t)N * sizeof(int);
    float* dis = (float*)w; w += (size_t)N * sizeof(float);
    int* starts = (int*)w;  w += (size_t)(G + 1) * sizeof(int);

    const size_t wo1 = 0;
    const size_t wo2 = (size_t)HID * F_IN;
    const size_t wo3 = wo2 + (size_t)HID * HID;
    const size_t wo4 = wo3 + (size_t)HID * HID;

    const int TB = 256;
    // ---- preprocessing ----
    pool_init_kernel<<<(G * 4096 + TB - 1) / TB, TB, 0, stream>>>((unsigned*)out, G * 4096);
    zero_kernel<<<(N + TB - 1) / TB, TB, 0, stream>>>(cnt, N);
    count_in_kernel<<<(E + TB - 1) / TB, TB, 0, stream>>>(dst, cnt, E);
    scan_kernel<<<1, 1024, 0, stream>>>(cnt, offs, N);
    dis_starts_kernel<<<(N + TB - 1) / TB, TB, 0, stream>>>(offs, dis, batch, starts, N, G);
    fill_csr_kernel<<<(E + TB - 1) / TB, TB, 0, stream>>>(src, dst, offs, cnt, csr, E);
    wconv_kernel<<<((int)nW + TB - 1) / TB, TB, 0, stream>>>(W1, W2, W3, W4, Whi, Wlo);

    dim3 gemm_grid((N + 127) / 128, HID / 128);
    const int ngrp = (N + 3) / 4;   // 4 nodes per agg block (one per wave)

    // ---- layer 1 ----
    agg_chunk_kernel<F_IN, 2><<<ngrp * 2, 256, 0, stream>>>(x, dis, offs, csr, Ahi, Alo, N);
    gemm_mfma_kernel<<<gemm_grid, 256, 0, stream>>>(Ahi, Alo, Whi + wo1, Wlo + wo1, b1, H,
                                                    batch, out, 0, 1, N, F_IN, HID);

    // ---- layers 2..4 ----
    const size_t wos[3] = {wo2, wo3, wo4};
    const float* bs_[3] = {b2, b3, b4};
    for (int ll = 0; ll < 3; ll++) {
        agg_chunk_kernel<HID, 8><<<ngrp * 8, 256, 0, stream>>>(H, dis, offs, csr, Ahi, Alo, N);
        gemm_mfma_kernel<<<gemm_grid, 256, 0, stream>>>(Ahi, Alo, Whi + wos[ll], Wlo + wos[ll], bs_[ll], H,
                                                        batch, out, ll + 1, (ll < 2) ? 1 : 0, N, HID, HID);
    }

    // ---- finalize pooling (decode max keys, counts -> fractions) ----
    pool_fin_kernel<<<(G * 2048 + TB - 1) / TB, TB, 0, stream>>>(out, starts, G);
}

// Round 6
// 678.979 us; speedup vs baseline: 1.2833x; 1.2833x over previous
//
#include <hip/hip_runtime.h>
#include <cfloat>
#include <cmath>

#define F_IN 128
#define HID 512

typedef short bf16x8 __attribute__((ext_vector_type(8)));
typedef float f32x4 __attribute__((ext_vector_type(4)));

// ---- bf16 split helpers (RNE) ----
__device__ static inline void split_bf16(float v, short& hi, short& lo) {
    unsigned u = __float_as_uint(v);
    unsigned r = u + 0x7FFF + ((u >> 16) & 1);
    hi = (short)(r >> 16);
    float hf = __uint_as_float(((unsigned)(unsigned short)hi) << 16);
    float res = v - hf;
    unsigned u2 = __float_as_uint(res);
    unsigned r2 = u2 + 0x7FFF + ((u2 >> 16) & 1);
    lo = (short)(r2 >> 16);
}

__device__ static inline void gload_lds16(const void* g, void* l) {
    __builtin_amdgcn_global_load_lds(
        (const __attribute__((address_space(1))) unsigned int*)g,
        (__attribute__((address_space(3))) unsigned int*)l,
        16, 0, 0);
}

// ---------------- small utility kernels ----------------

__global__ void zero_kernel(int* __restrict__ a, int n) {
    int i = blockIdx.x * blockDim.x + threadIdx.x;
    if (i < n) a[i] = 0;
}

__global__ void count_in_kernel(const int* __restrict__ dst, int* __restrict__ cnt, int E) {
    int e = blockIdx.x * blockDim.x + threadIdx.x;
    if (e < E) atomicAdd(&cnt[dst[e]], 1);
}

// single-block scan (exclusive prefix sum); also writes offs[n] = total
__global__ void scan_kernel(const int* __restrict__ cnt, int* __restrict__ offs, int n) {
    __shared__ int buf[1024];
    __shared__ int carry_s;
    if (threadIdx.x == 0) carry_s = 0;
    __syncthreads();
    for (int base = 0; base < n; base += 1024) {
        int i = base + threadIdx.x;
        int v = (i < n) ? cnt[i] : 0;
        buf[threadIdx.x] = v;
        __syncthreads();
        for (int s = 1; s < 1024; s <<= 1) {
            int t = (threadIdx.x >= s) ? buf[threadIdx.x - s] : 0;
            __syncthreads();
            buf[threadIdx.x] += t;
            __syncthreads();
        }
        int total = buf[1023];
        if (i < n) offs[i] = carry_s + buf[threadIdx.x] - v;
        __syncthreads();
        if (threadIdx.x == 0) carry_s += total;
        __syncthreads();
    }
    if (threadIdx.x == 0) offs[n] = carry_s;
}

// dis + graph-boundary starts, merged (both N-grids)
__global__ void dis_starts_kernel(const int* __restrict__ offs, float* __restrict__ dis,
                                  const int* __restrict__ batch, int* __restrict__ starts,
                                  int n, int G) {
    int i = blockIdx.x * blockDim.x + threadIdx.x;
    if (i >= n) return;
    dis[i] = rsqrtf((float)(offs[i + 1] - offs[i] + 1));  // +1 self-loop
    int b = batch[i];
    if (i == 0) {
        for (int g = 0; g <= b; g++) starts[g] = 0;
    } else {
        int bp = batch[i - 1];
        for (int g = bp + 1; g <= b; g++) starts[g] = i;
    }
    if (i == n - 1) {
        for (int g = b + 1; g <= G; g++) starts[g] = n;
    }
}

// countdown-cursor fill: reuses cnt (holds deg) as cursor via atomicSub
__global__ void fill_csr_kernel(const int* __restrict__ src, const int* __restrict__ dst,
                                const int* __restrict__ offs, int* __restrict__ cnt,
                                unsigned short* __restrict__ csr, int E) {
    int e = blockIdx.x * blockDim.x + threadIdx.x;
    if (e < E) {
        int d = dst[e];
        int p = atomicSub(&cnt[d], 1);  // returns old value in [1, deg]
        csr[offs[d] + p - 1] = (unsigned short)src[e];
    }
}

// all-layer W fp32 -> bf16 hi/lo planes (single launch, concatenated)
__global__ void wconv_kernel(const float* __restrict__ W1, const float* __restrict__ W2,
                             const float* __restrict__ W3, const float* __restrict__ W4,
                             short* __restrict__ Whi, short* __restrict__ Wlo) {
    int i = blockIdx.x * blockDim.x + threadIdx.x;
    const int n1 = HID * F_IN, nk = HID * HID;
    float v;
    if (i < n1) v = W1[i];
    else if (i < n1 + nk) v = W2[i - n1];
    else if (i < n1 + 2 * nk) v = W3[i - n1 - nk];
    else if (i < n1 + 3 * nk) v = W4[i - n1 - 2 * nk];
    else return;
    short h, l;
    split_bf16(v, h, l);
    Whi[i] = h;
    Wlo[i] = l;
}

// -------- XCD-affine chunked aggregation + fused bf16-pair conversion --------
// out_i = dis_i * (dis_i*H_i + sum_j dis_j*H_j), written as bf16 hi/lo planes.
// blk = node*CHUNKS + chunk; chunk == blk % CHUNKS tracks round-robin
// workgroup->XCD mapping: each XCD's L2 sees only its 64-col slice of H
// (5.1 MB vs 41 MB). One wave per block (R3-measured best: 85 us; 2- and
// 4-node blocks regressed via tail/load-imbalance — R4/R5).
template <int F, int CHUNKS>
__global__ __launch_bounds__(64) void agg_chunk_kernel(
    const float* __restrict__ H, const float* __restrict__ dis,
    const int* __restrict__ offs, const unsigned short* __restrict__ csr,
    short* __restrict__ Ahi, short* __restrict__ Alo, int n) {
    int blk = blockIdx.x;
    int i = blk / CHUNKS;
    int chunk = blk % CHUNKS;
    int col = chunk * 64 + threadIdx.x;
    const float* Hc = H + col;

    float di = dis[i];
    float a = di * Hc[(size_t)i * F];
    int e = offs[i], e1 = offs[i + 1];
    // 8-way software-pipelined gather
    for (; e + 8 <= e1; e += 8) {
        int j0 = csr[e],     j1 = csr[e + 1], j2 = csr[e + 2], j3 = csr[e + 3];
        int j4 = csr[e + 4], j5 = csr[e + 5], j6 = csr[e + 6], j7 = csr[e + 7];
        float d0 = dis[j0], d1 = dis[j1], d2 = dis[j2], d3 = dis[j3];
        float d4 = dis[j4], d5 = dis[j5], d6 = dis[j6], d7 = dis[j7];
        float r0 = Hc[(size_t)j0 * F], r1 = Hc[(size_t)j1 * F];
        float r2 = Hc[(size_t)j2 * F], r3 = Hc[(size_t)j3 * F];
        float r4 = Hc[(size_t)j4 * F], r5 = Hc[(size_t)j5 * F];
        float r6 = Hc[(size_t)j6 * F], r7 = Hc[(size_t)j7 * F];
        a += d0 * r0 + d1 * r1 + d2 * r2 + d3 * r3;
        a += d4 * r4 + d5 * r5 + d6 * r6 + d7 * r7;
    }
    for (; e < e1; e++) {
        int j = csr[e];
        a += dis[j] * Hc[(size_t)j * F];
    }
    a *= di;
    short h, l;
    split_bf16(a, h, l);
    Ahi[(size_t)i * F + col] = h;
    Alo[(size_t)i * F + col] = l;
}

// -------- split-bf16 MFMA GEMM: C[M,N] = A[M,K] @ W[N,K]^T + bias --------
// A,W as bf16 hi/lo planes; 3 products hi*hi + hi*lo + lo*hi.
// 1D grid, XCD-affine swizzle: xcd = blk&7 owns a contiguous band of M-tiles,
// so each XCD's 4 MiB L2 re-reads a ~5 MB A-band instead of the full 41 MB.
// Plain epilogue (R3-proven; fused pooling measured -20..-37 us/GEMM, reverted).
__global__ __launch_bounds__(256) void gemm_mfma_kernel(
    const short* __restrict__ Ahi, const short* __restrict__ Alo,
    const short* __restrict__ Whi, const short* __restrict__ Wlo,
    const float* __restrict__ bias, float* __restrict__ C,
    int M, int K, int Nout, int MT, int MT8) {
    __shared__ __attribute__((aligned(16))) short lds[4][4096];

    // swizzled block decode: blk = xcd + 8*(n0t + 4*mt_local)
    int blk = blockIdx.x;
    int xcd = blk & 7;
    int r = blk >> 3;
    int n0t = r & 3;
    int mt = xcd * MT8 + (r >> 2);
    if (mt >= MT) return;                 // uniform across block; no barrier reached
    int m0 = mt * 128, n0 = n0t * 128;

    int tid = threadIdx.x;
    int w = tid >> 6, l = tid & 63;
    int lrow = l & 15, lq = l >> 4;

    const short* gp = (w == 0) ? Ahi : (w == 1) ? Alo : (w == 2) ? Whi : Wlo;
    int base_mn = (w < 2) ? m0 : n0;

    f32x4 acc[4][4];
    #pragma unroll
    for (int i = 0; i < 4; i++)
        #pragma unroll
        for (int j = 0; j < 4; j++) acc[i][j] = (f32x4){0.f, 0.f, 0.f, 0.f};

    int wm = w >> 1, wn = w & 1;

    for (int k0 = 0; k0 < K; k0 += 32) {
        const short* gbase = gp + (size_t)(base_mn + lrow) * K + (k0 + lq * 8);
        #pragma unroll
        for (int s = 0; s < 8; s++) {
            gload_lds16(gbase + (size_t)s * 16 * K, &lds[w][s * 64 * 8]);
        }
        __syncthreads();

        bf16x8 ah[4], al[4], wh[4], wl[4];
        #pragma unroll
        for (int i = 0; i < 4; i++) {
            int sA = wm * 4 + i;
            ah[i] = *(const bf16x8*)&lds[0][(sA * 64 + l) * 8];
            al[i] = *(const bf16x8*)&lds[1][(sA * 64 + l) * 8];
            int sW = wn * 4 + i;
            wh[i] = *(const bf16x8*)&lds[2][(sW * 64 + l) * 8];
            wl[i] = *(const bf16x8*)&lds[3][(sW * 64 + l) * 8];
        }
        #pragma unroll
        for (int i = 0; i < 4; i++)
            #pragma unroll
            for (int j = 0; j < 4; j++) {
                acc[i][j] = __builtin_amdgcn_mfma_f32_16x16x32_bf16(ah[i], wh[j], acc[i][j], 0, 0, 0);
                acc[i][j] = __builtin_amdgcn_mfma_f32_16x16x32_bf16(ah[i], wl[j], acc[i][j], 0, 0, 0);
                acc[i][j] = __builtin_amdgcn_mfma_f32_16x16x32_bf16(al[i], wh[j], acc[i][j], 0, 0, 0);
            }
        __syncthreads();
    }

    // epilogue: C/D layout col=lane&15, row=(lane>>4)*4+reg
    #pragma unroll
    for (int j = 0; j < 4; j++) {
        int col = n0 + (wn * 4 + j) * 16 + lrow;
        float bv = bias[col];
        #pragma unroll
        for (int i = 0; i < 4; i++) {
            int mrow = m0 + (wm * 4 + i) * 16 + lq * 4;
            #pragma unroll
            for (int rr = 0; rr < 4; rr++) {
                int mm = mrow + rr;
                if (mm < M) C[(size_t)mm * Nout + col] = acc[i][j][rr] + bv;
            }
        }
    }
}

// ---------------- pooling: per-layer segment max + fraction positive ----------------
// grid (G, 8), 64 threads: 2048 blocks for CU coverage.
__global__ __launch_bounds__(64) void pool_kernel(
    const float* __restrict__ H, const int* __restrict__ starts,
    float* __restrict__ out, int layer) {
    int g = blockIdx.x;
    int c = blockIdx.y * 64 + threadIdx.x;   // 0..511
    int s = starts[g], e = starts[g + 1];
    float mx = -INFINITY;
    int pos = 0;
    #pragma unroll 4
    for (int n = s; n < e; n++) {
        float v = H[(size_t)n * HID + c];
        mx = fmaxf(mx, v);
        pos += (v > 0.0f) ? 1 : 0;
    }
    float cntf = fmaxf((float)(e - s), 1.0f);
    out[(size_t)g * (8 * HID) + layer * HID + c] = mx;
    out[(size_t)g * (8 * HID) + 4 * HID + layer * HID + c] = (float)pos / cntf;
}

// ---------------- launcher ----------------
extern "C" void kernel_launch(void* const* d_in, const int* in_sizes, int n_in,
                              void* d_out, int out_size, void* d_ws, size_t ws_size,
                              hipStream_t stream) {
    const float* x     = (const float*)d_in[0];
    const int*   eidx  = (const int*)d_in[1];
    const int*   batch = (const int*)d_in[2];
    const float* W1 = (const float*)d_in[5];
    const float* b1 = (const float*)d_in[6];
    const float* W2 = (const float*)d_in[7];
    const float* b2 = (const float*)d_in[8];
    const float* W3 = (const float*)d_in[9];
    const float* b3 = (const float*)d_in[10];
    const float* W4 = (const float*)d_in[11];
    const float* b4 = (const float*)d_in[12];
    float* out = (float*)d_out;

    const int N = in_sizes[0] / F_IN;   // 20000
    const int E = in_sizes[1] / 2;      // 320000
    const int G = out_size / (8 * HID); // 256

    const int* src = eidx;
    const int* dst = eidx + E;

    // workspace layout (16B-aligned segments first)
    const size_t nW = (size_t)HID * F_IN + 3 * (size_t)HID * HID;
    char* w = (char*)d_ws;
    short* Ahi = (short*)w; w += (size_t)N * HID * sizeof(short);
    short* Alo = (short*)w; w += (size_t)N * HID * sizeof(short);
    float* H   = (float*)w; w += (size_t)N * HID * sizeof(float);
    short* Whi = (short*)w; w += nW * sizeof(short);
    short* Wlo = (short*)w; w += nW * sizeof(short);
    int* offs  = (int*)w;   w += (size_t)(N + 4) * sizeof(int);
    unsigned short* csr = (unsigned short*)w; w += (size_t)E * sizeof(unsigned short);
    int* cnt   = (int*)w;   w += (size_t)N * sizeof(int);
    float* dis = (float*)w; w += (size_t)N * sizeof(float);
    int* starts = (int*)w;  w += (size_t)(G + 1) * sizeof(int);

    const size_t wo1 = 0;
    const size_t wo2 = (size_t)HID * F_IN;
    const size_t wo3 = wo2 + (size_t)HID * HID;
    const size_t wo4 = wo3 + (size_t)HID * HID;

    const int TB = 256;
    // ---- preprocessing: CSR over dst, dis, graph boundaries, W planes ----
    zero_kernel<<<(N + TB - 1) / TB, TB, 0, stream>>>(cnt, N);
    count_in_kernel<<<(E + TB - 1) / TB, TB, 0, stream>>>(dst, cnt, E);
    scan_kernel<<<1, 1024, 0, stream>>>(cnt, offs, N);
    dis_starts_kernel<<<(N + TB - 1) / TB, TB, 0, stream>>>(offs, dis, batch, starts, N, G);
    fill_csr_kernel<<<(E + TB - 1) / TB, TB, 0, stream>>>(src, dst, offs, cnt, csr, E);
    wconv_kernel<<<((int)nW + TB - 1) / TB, TB, 0, stream>>>(W1, W2, W3, W4, Whi, Wlo);

    const int MT = (N + 127) / 128;        // 157 m-tiles
    const int MT8 = (MT + 7) / 8;          // per-XCD band
    const int gemm_blocks = 8 * MT8 * 4;   // 1D swizzled grid (some idle-guarded)
    dim3 pool_grid(G, HID / 64);

    // ---- layer 1: h1 = (A x) @ W1^T + b1 ----
    agg_chunk_kernel<F_IN, 2><<<N * 2, 64, 0, stream>>>(x, dis, offs, csr, Ahi, Alo, N);
    gemm_mfma_kernel<<<gemm_blocks, 256, 0, stream>>>(Ahi, Alo, Whi + wo1, Wlo + wo1, b1, H,
                                                      N, F_IN, HID, MT, MT8);
    pool_kernel<<<pool_grid, 64, 0, stream>>>(H, starts, out, 0);

    // ---- layers 2..4 ----
    const size_t wos[3] = {wo2, wo3, wo4};
    const float* bs_[3] = {b2, b3, b4};
    for (int ll = 0; ll < 3; ll++) {
        agg_chunk_kernel<HID, 8><<<N * 8, 64, 0, stream>>>(H, dis, offs, csr, Ahi, Alo, N);
        gemm_mfma_kernel<<<gemm_blocks, 256, 0, stream>>>(Ahi, Alo, Whi + wos[ll], Wlo + wos[ll], bs_[ll], H,
                                                          N, HID, HID, MT, MT8);
        pool_kernel<<<pool_grid, 64, 0, stream>>>(H, starts, out, ll + 1);
    }
}